// Round 1
// baseline (718.775 us; speedup 1.0000x reference)
//
#include <hip/hip_runtime.h>

#define DEV __device__ __forceinline__

typedef unsigned short u16;
typedef unsigned int u32;
using bf16x8 = __attribute__((ext_vector_type(8))) __bf16;
using f32x4v = __attribute__((ext_vector_type(4))) float;

typedef __attribute__((address_space(1))) void gas_void;
typedef __attribute__((address_space(3))) void las_void;

DEV u16 f32_bf16(float f){
  u32 u = __float_as_uint(f);
  u += 0x7FFFu + ((u >> 16) & 1u);   // RNE
  return (u16)(u >> 16);
}
DEV float bf16_f32(u16 h){ return __uint_as_float(((u32)h) << 16); }

DEV void gload16(const void* g, void* l){
  __builtin_amdgcn_global_load_lds((gas_void*)g, (las_void*)l, 16, 0, 0);
}

// ---------------- prep: x f32 -> bf16 ----------------
__global__ void cvt_f32_bf16_k(const float* __restrict__ in, u16* __restrict__ out, int n){
  int i = (blockIdx.x * 256 + threadIdx.x) * 8;
  if (i >= n) return;
  float4 a = *(const float4*)(in + i);
  float4 b = *(const float4*)(in + i + 4);
  uint4 r;
  r.x = (u32)f32_bf16(a.x) | ((u32)f32_bf16(a.y) << 16);
  r.y = (u32)f32_bf16(a.z) | ((u32)f32_bf16(a.w) << 16);
  r.z = (u32)f32_bf16(b.x) | ((u32)f32_bf16(b.y) << 16);
  r.w = (u32)f32_bf16(b.z) | ((u32)f32_bf16(b.w) << 16);
  *(uint4*)(out + i) = r;
}

// ------------- prep: transpose+convert, out[c][r] = in[r][c] -------------
// grid: (C/64, R/64, batch), block 256
template<typename T>
__global__ void transpose_cvt_k(const T* __restrict__ in, u16* __restrict__ out, int R, int C){
  in  += (size_t)blockIdx.z * R * C;
  out += (size_t)blockIdx.z * R * C;
  __shared__ float tile[64][65];
  int c0 = blockIdx.x * 64, r0 = blockIdx.y * 64;
  int t = threadIdx.x;
  int lr = t >> 4;         // 0..15
  int lc = (t & 15) * 4;   // 0..60
  #pragma unroll
  for (int p = 0; p < 4; p++){
    int row = p * 16 + lr;
    const T* src = in + (size_t)(r0 + row) * C + c0 + lc;
    float v0, v1, v2, v3;
    if constexpr (sizeof(T) == 4){
      float4 v = *(const float4*)src;
      v0 = v.x; v1 = v.y; v2 = v.z; v3 = v.w;
    } else {
      ushort4 v = *(const ushort4*)src;
      v0 = bf16_f32(v.x); v1 = bf16_f32(v.y); v2 = bf16_f32(v.z); v3 = bf16_f32(v.w);
    }
    tile[row][lc+0] = v0; tile[row][lc+1] = v1; tile[row][lc+2] = v2; tile[row][lc+3] = v3;
  }
  __syncthreads();
  #pragma unroll
  for (int p = 0; p < 4; p++){
    int ocol = p * 16 + lr;
    ushort4 w;
    w.x = f32_bf16(tile[lc+0][ocol]);
    w.y = f32_bf16(tile[lc+1][ocol]);
    w.z = f32_bf16(tile[lc+2][ocol]);
    w.w = f32_bf16(tile[lc+3][ocol]);
    *(ushort4*)(out + (size_t)(c0 + ocol) * R + r0 + lc) = w;
  }
}

// ---------------- GEMM: C[m][n] = sum_k A[m][k]*BT[n][k] + bias[n] ----------------
// 128x128 tile, BK=32, 256 thr (4 waves, 2x2), wave = 64x64 = 4x4 frags of 16x16x32.
// mode 0: write bf16 Q[B,H,S,D]; mode 1: split bf16 K/V [B,G,S,D]; mode 2: f32 [M][N].
__global__ __launch_bounds__(256, 2)
void gemm_bf16_k(const u16* __restrict__ A, const u16* __restrict__ BT,
                 const float* __restrict__ bias,
                 u16* __restrict__ outU0, u16* __restrict__ outU1,
                 float* __restrict__ outF,
                 int M, int N, int K, int mode)
{
  __shared__ __align__(16) u16 sA[2][128*32];
  __shared__ __align__(16) u16 sB[2][128*32];
  const int t = threadIdx.x;
  const int l = t & 63;
  const int wv = t >> 6;
  const int wm = wv >> 1, wn = wv & 1;
  const int rl = l & 15, gr = l >> 4;
  const size_t m0 = (size_t)blockIdx.x * 128, n0 = (size_t)blockIdx.y * 128;

  const u16* gA = A + m0 * K;
  const u16* gB = BT + n0 * K;

  f32x4v acc[4][4];
  #pragma unroll
  for (int i = 0; i < 4; i++)
    #pragma unroll
    for (int j = 0; j < 4; j++)
      acc[i][j] = (f32x4v)(0.0f);

  auto stage = [&](int buf, int kt){
    const size_t k0 = (size_t)kt * 32;
    #pragma unroll
    for (int i = 0; i < 2; i++){
      int c = i * 256 + t;            // 0..511 chunk id
      int row = c >> 2, kc = c & 3;   // row 0..127, 8-elem k-chunk
      gload16(gA + (size_t)row * K + k0 + kc * 8, &sA[buf][c * 8]);
      gload16(gB + (size_t)row * K + k0 + kc * 8, &sB[buf][c * 8]);
    }
  };

  auto compute = [&](int buf){
    const u16* sa = sA[buf];
    const u16* sb = sB[buf];
    bf16x8 af[4], bfr[4];
    #pragma unroll
    for (int mr = 0; mr < 4; mr++)
      af[mr] = *(const bf16x8*)(sa + (wm*64 + mr*16 + rl)*32 + gr*8);
    #pragma unroll
    for (int nr = 0; nr < 4; nr++)
      bfr[nr] = *(const bf16x8*)(sb + (wn*64 + nr*16 + rl)*32 + gr*8);
    #pragma unroll
    for (int mr = 0; mr < 4; mr++)
      #pragma unroll
      for (int nr = 0; nr < 4; nr++)
        acc[mr][nr] = __builtin_amdgcn_mfma_f32_16x16x32_bf16(af[mr], bfr[nr], acc[mr][nr], 0, 0, 0);
  };

  stage(0, 0);
  asm volatile("s_waitcnt vmcnt(0)" ::: "memory");
  __syncthreads();
  const int NT = K / 32;
  for (int kt = 0; kt < NT; kt++){
    int cur = kt & 1;
    if (kt + 1 < NT) stage(cur ^ 1, kt + 1);
    compute(cur);
    asm volatile("s_waitcnt vmcnt(0)" ::: "memory");
    __syncthreads();
  }

  #pragma unroll
  for (int nr = 0; nr < 4; nr++){
    int col = (int)n0 + wn*64 + nr*16 + rl;
    float bv = bias[col];
    #pragma unroll
    for (int mr = 0; mr < 4; mr++){
      int rowb = (int)m0 + wm*64 + mr*16 + gr*4;
      #pragma unroll
      for (int r = 0; r < 4; r++){
        int row = rowb + r;
        float v = acc[mr][nr][r] + bv;
        if (mode == 2){
          outF[(size_t)row * N + col] = v;
        } else if (mode == 0){
          int b = row >> 11, s = row & 2047, h = col >> 7, d = col & 127;
          outU0[(((size_t)(b*16 + h)) * 2048 + s) * 128 + d] = f32_bf16(v);
        } else {
          int b = row >> 11, s = row & 2047, g = col >> 8, c = col & 255;
          u16* dst = (c < 128) ? outU0 : outU1;
          dst[(((size_t)(b*4 + g)) * 2048 + s) * 128 + (c & 127)] = f32_bf16(v);
        }
      }
    }
  }
}

// ---------------- flash attention ----------------
// grid (S/64, B*H), 256 thr; each wave owns 16 q-rows, loops 64-key tiles.
// Swapped QK^T: S^T = mfma(K, Q) so per-q softmax stats are lane-local (q = l&15).
__global__ __launch_bounds__(256, 2)
void attn_k(const u16* __restrict__ Q, const u16* __restrict__ Kb,
            const u16* __restrict__ VT, u16* __restrict__ O)
{
  __shared__ __align__(16) u16 Plds[4][16*72];   // per-wave P buffer, padded stride 72
  const int t = threadIdx.x, l = t & 63, wv = t >> 6;
  const int rl = l & 15, gr = l >> 4;
  const int bh = blockIdx.y;
  const int b = bh >> 4, h = bh & 15, g = h >> 2;
  const int q0 = blockIdx.x * 64 + wv * 16;
  const u16* Qp = Q + ((size_t)(b*16 + h) * 2048 + q0) * 128;
  const u16* Kp = Kb + (size_t)(b*4 + g) * 2048 * 128;
  const u16* Vp = VT + (size_t)(b*4 + g) * 128 * 2048;   // VT[d][s]

  bf16x8 qf[4];
  #pragma unroll
  for (int ds = 0; ds < 4; ds++)
    qf[ds] = *(const bf16x8*)(Qp + rl*128 + ds*32 + gr*8);

  f32x4v acc_o[8];
  #pragma unroll
  for (int i = 0; i < 8; i++) acc_o[i] = (f32x4v)(0.0f);
  float m_run = -3.0e38f, l_run = 0.0f;
  const float scale = 0.0883883476483184f;   // 1/sqrt(128)

  for (int kt = 0; kt < 32; kt++){
    const int kv0 = kt * 64;
    float pv[4][4];
    float tm = -3.0e38f;
    #pragma unroll
    for (int tt = 0; tt < 4; tt++){
      f32x4v st = (f32x4v)(0.0f);
      #pragma unroll
      for (int ds = 0; ds < 4; ds++){
        bf16x8 kf = *(const bf16x8*)(Kp + (size_t)(kv0 + tt*16 + rl) * 128 + ds*32 + gr*8);
        st = __builtin_amdgcn_mfma_f32_16x16x32_bf16(kf, qf[ds], st, 0, 0, 0);
      }
      #pragma unroll
      for (int r = 0; r < 4; r++){
        float s = st[r] * scale;
        pv[tt][r] = s;
        tm = fmaxf(tm, s);
      }
    }
    // reduce over the 4 lane-groups holding the same q (= l&15)
    tm = fmaxf(tm, __shfl_xor(tm, 16, 64));
    tm = fmaxf(tm, __shfl_xor(tm, 32, 64));
    float m_new = fmaxf(m_run, tm);
    float corr = __expf(m_run - m_new);     // exp(-inf)=0 on first tile
    float psum = 0.f;
    #pragma unroll
    for (int tt = 0; tt < 4; tt++)
      #pragma unroll
      for (int r = 0; r < 4; r++){
        float p = __expf(pv[tt][r] - m_new);
        pv[tt][r] = p;
        psum += p;
      }
    psum += __shfl_xor(psum, 16, 64);
    psum += __shfl_xor(psum, 32, 64);
    l_run = l_run * corr + psum;
    m_run = m_new;
    // rescale O: O-rows are q=(gr*4+r); fetch corr from lane q (which has l&15==q)
    float cr0 = __shfl(corr, gr*4 + 0, 64);
    float cr1 = __shfl(corr, gr*4 + 1, 64);
    float cr2 = __shfl(corr, gr*4 + 2, 64);
    float cr3 = __shfl(corr, gr*4 + 3, 64);
    #pragma unroll
    for (int dc = 0; dc < 8; dc++){
      acc_o[dc][0] *= cr0; acc_o[dc][1] *= cr1; acc_o[dc][2] *= cr2; acc_o[dc][3] *= cr3;
    }
    // P (S^T layout) -> LDS as P[q][kv] bf16, then re-read as A-fragments
    #pragma unroll
    for (int tt = 0; tt < 4; tt++){
      ushort4 pk;
      pk.x = f32_bf16(pv[tt][0]); pk.y = f32_bf16(pv[tt][1]);
      pk.z = f32_bf16(pv[tt][2]); pk.w = f32_bf16(pv[tt][3]);
      *(ushort4*)&Plds[wv][rl*72 + tt*16 + gr*4] = pk;
    }
    asm volatile("s_waitcnt lgkmcnt(0)" ::: "memory");
    #pragma unroll
    for (int kc = 0; kc < 2; kc++){
      bf16x8 pa = *(const bf16x8*)&Plds[wv][rl*72 + kc*32 + gr*8];
      #pragma unroll
      for (int dc = 0; dc < 8; dc++){
        bf16x8 vf = *(const bf16x8*)(Vp + (size_t)(dc*16 + rl) * 2048 + kv0 + kc*32 + gr*8);
        acc_o[dc] = __builtin_amdgcn_mfma_f32_16x16x32_bf16(pa, vf, acc_o[dc], 0, 0, 0);
      }
    }
  }
  float linv = 1.0f / l_run;
  float lr0 = __shfl(linv, gr*4 + 0, 64);
  float lr1 = __shfl(linv, gr*4 + 1, 64);
  float lr2 = __shfl(linv, gr*4 + 2, 64);
  float lr3 = __shfl(linv, gr*4 + 3, 64);
  float lrr[4] = {lr0, lr1, lr2, lr3};
  #pragma unroll
  for (int dc = 0; dc < 8; dc++)
    #pragma unroll
    for (int r = 0; r < 4; r++){
      size_t idx = ((size_t)b * 2048 + q0 + gr*4 + r) * 2048 + h*128 + dc*16 + rl;
      O[idx] = f32_bf16(acc_o[dc][r] * lrr[r]);
    }
}

extern "C" void kernel_launch(void* const* d_in, const int* in_sizes, int n_in,
                              void* d_out, int out_size, void* d_ws, size_t ws_size,
                              hipStream_t stream)
{
  const float* x   = (const float*)d_in[0];
  const float* Wq  = (const float*)d_in[1];
  const float* bq  = (const float*)d_in[2];
  const float* Wkv = (const float*)d_in[3];
  const float* bkv = (const float*)d_in[4];
  const float* Wo  = (const float*)d_in[5];
  const float* bo  = (const float*)d_in[6];
  float* out = (float*)d_out;

  char* ws = (char*)d_ws;
  size_t off = 0;
  auto alloc = [&](size_t bytes){ void* p = ws + off; off = (off + bytes + 255) & ~(size_t)255; return p; };
  u16* xb   = (u16*)alloc(8388608ull * 2);   // x bf16 [4096][2048]
  u16* WqT  = (u16*)alloc(4194304ull * 2);   // [2048][2048]
  u16* WkvT = (u16*)alloc(2097152ull * 2);   // [1024][2048]
  u16* WoT  = (u16*)alloc(4194304ull * 2);   // [2048][2048]
  u16* Qb   = (u16*)alloc(8388608ull * 2);   // [B,H,S,D]
  u16* Kb   = (u16*)alloc(2097152ull * 2);   // [B,G,S,D]
  u16* Vb   = (u16*)alloc(2097152ull * 2);   // [B,G,S,D]
  u16* VTb  = (u16*)alloc(2097152ull * 2);   // [B,G,D,S]
  u16* Ob   = (u16*)alloc(8388608ull * 2);   // [B,S,E]

  cvt_f32_bf16_k<<<4096, 256, 0, stream>>>(x, xb, 8388608);
  transpose_cvt_k<float><<<dim3(32, 32, 1), 256, 0, stream>>>(Wq,  WqT,  2048, 2048);
  transpose_cvt_k<float><<<dim3(16, 32, 1), 256, 0, stream>>>(Wkv, WkvT, 2048, 1024);
  transpose_cvt_k<float><<<dim3(32, 32, 1), 256, 0, stream>>>(Wo,  WoT,  2048, 2048);

  gemm_bf16_k<<<dim3(32, 16), 256, 0, stream>>>(xb, WqT,  bq,  Qb, nullptr, nullptr, 4096, 2048, 2048, 0);
  gemm_bf16_k<<<dim3(32, 8),  256, 0, stream>>>(xb, WkvT, bkv, Kb, Vb,      nullptr, 4096, 1024, 2048, 1);

  transpose_cvt_k<u16><<<dim3(2, 32, 8), 256, 0, stream>>>(Vb, VTb, 2048, 128);

  attn_k<<<dim3(32, 32), 256, 0, stream>>>(Qb, Kb, VTb, Ob);

  gemm_bf16_k<<<dim3(32, 16), 256, 0, stream>>>(Ob, WoT, bo, nullptr, nullptr, out, 4096, 2048, 2048, 2);
}

// Round 2
// 391.003 us; speedup vs baseline: 1.8383x; 1.8383x over previous
//
#include <hip/hip_runtime.h>

#define DEV __device__ __forceinline__

typedef unsigned short u16;
typedef unsigned int u32;
using bf16x8 = __attribute__((ext_vector_type(8))) __bf16;
using f32x4v = __attribute__((ext_vector_type(4))) float;

typedef __attribute__((address_space(1))) void gas_void;
typedef __attribute__((address_space(3))) void las_void;

DEV u16 f32_bf16(float f){
  u32 u = __float_as_uint(f);
  u += 0x7FFFu + ((u >> 16) & 1u);   // RNE
  return (u16)(u >> 16);
}
DEV float bf16_f32(u16 h){ return __uint_as_float(((u32)h) << 16); }

DEV void gload16(const void* g, void* l){
  __builtin_amdgcn_global_load_lds((gas_void*)g, (las_void*)l, 16, 0, 0);
}

// ---------------- prep: x f32 -> bf16 ----------------
__global__ void cvt_f32_bf16_k(const float* __restrict__ in, u16* __restrict__ out, int n){
  int i = (blockIdx.x * 256 + threadIdx.x) * 8;
  if (i >= n) return;
  float4 a = *(const float4*)(in + i);
  float4 b = *(const float4*)(in + i + 4);
  uint4 r;
  r.x = (u32)f32_bf16(a.x) | ((u32)f32_bf16(a.y) << 16);
  r.y = (u32)f32_bf16(a.z) | ((u32)f32_bf16(a.w) << 16);
  r.z = (u32)f32_bf16(b.x) | ((u32)f32_bf16(b.y) << 16);
  r.w = (u32)f32_bf16(b.z) | ((u32)f32_bf16(b.w) << 16);
  *(uint4*)(out + i) = r;
}

// ------------- prep: transpose+convert, out[c][r] = in[r][c] -------------
// grid: (C/64, R/64, batch), block 256
template<typename T>
__global__ void transpose_cvt_k(const T* __restrict__ in, u16* __restrict__ out, int R, int C){
  in  += (size_t)blockIdx.z * R * C;
  out += (size_t)blockIdx.z * R * C;
  __shared__ float tile[64][65];
  int c0 = blockIdx.x * 64, r0 = blockIdx.y * 64;
  int t = threadIdx.x;
  int lr = t >> 4;         // 0..15
  int lc = (t & 15) * 4;   // 0..60
  #pragma unroll
  for (int p = 0; p < 4; p++){
    int row = p * 16 + lr;
    const T* src = in + (size_t)(r0 + row) * C + c0 + lc;
    float v0, v1, v2, v3;
    if constexpr (sizeof(T) == 4){
      float4 v = *(const float4*)src;
      v0 = v.x; v1 = v.y; v2 = v.z; v3 = v.w;
    } else {
      ushort4 v = *(const ushort4*)src;
      v0 = bf16_f32(v.x); v1 = bf16_f32(v.y); v2 = bf16_f32(v.z); v3 = bf16_f32(v.w);
    }
    tile[row][lc+0] = v0; tile[row][lc+1] = v1; tile[row][lc+2] = v2; tile[row][lc+3] = v3;
  }
  __syncthreads();
  #pragma unroll
  for (int p = 0; p < 4; p++){
    int ocol = p * 16 + lr;
    ushort4 w;
    w.x = f32_bf16(tile[lc+0][ocol]);
    w.y = f32_bf16(tile[lc+1][ocol]);
    w.z = f32_bf16(tile[lc+2][ocol]);
    w.w = f32_bf16(tile[lc+3][ocol]);
    *(ushort4*)(out + (size_t)(c0 + ocol) * R + r0 + lc) = w;
  }
}

// ---------------- GEMM: C[m][n] = sum_k A[m][k]*BT[n][k] + bias[n] ----------------
// 128x128 tile, BK=32, 256 thr (4 waves, 2x2), wave = 64x64 = 4x4 frags of 16x16x32.
// mode 0: write bf16 Q[B,H,S,D]; mode 1: split bf16 K/V [B,G,S,D]; mode 2: f32 [M][N].
__global__ __launch_bounds__(256, 2)
void gemm_bf16_k(const u16* __restrict__ A, const u16* __restrict__ BT,
                 const float* __restrict__ bias,
                 u16* __restrict__ outU0, u16* __restrict__ outU1,
                 float* __restrict__ outF,
                 int M, int N, int K, int mode)
{
  __shared__ __align__(16) u16 sA[2][128*32];
  __shared__ __align__(16) u16 sB[2][128*32];
  const int t = threadIdx.x;
  const int l = t & 63;
  const int wv = t >> 6;
  const int wm = wv >> 1, wn = wv & 1;
  const int rl = l & 15, gr = l >> 4;
  const size_t m0 = (size_t)blockIdx.x * 128, n0 = (size_t)blockIdx.y * 128;

  const u16* gA = A + m0 * K;
  const u16* gB = BT + n0 * K;

  f32x4v acc[4][4];
  #pragma unroll
  for (int i = 0; i < 4; i++)
    #pragma unroll
    for (int j = 0; j < 4; j++)
      acc[i][j] = (f32x4v)(0.0f);

  auto stage = [&](int buf, int kt){
    const size_t k0 = (size_t)kt * 32;
    #pragma unroll
    for (int i = 0; i < 2; i++){
      int c = i * 256 + t;            // 0..511 chunk id
      int row = c >> 2, kc = c & 3;   // row 0..127, 8-elem k-chunk
      gload16(gA + (size_t)row * K + k0 + kc * 8, &sA[buf][c * 8]);
      gload16(gB + (size_t)row * K + k0 + kc * 8, &sB[buf][c * 8]);
    }
  };

  auto compute = [&](int buf){
    const u16* sa = sA[buf];
    const u16* sb = sB[buf];
    bf16x8 af[4], bfr[4];
    #pragma unroll
    for (int mr = 0; mr < 4; mr++)
      af[mr] = *(const bf16x8*)(sa + (wm*64 + mr*16 + rl)*32 + gr*8);
    #pragma unroll
    for (int nr = 0; nr < 4; nr++)
      bfr[nr] = *(const bf16x8*)(sb + (wn*64 + nr*16 + rl)*32 + gr*8);
    __builtin_amdgcn_s_setprio(1);
    #pragma unroll
    for (int mr = 0; mr < 4; mr++)
      #pragma unroll
      for (int nr = 0; nr < 4; nr++)
        acc[mr][nr] = __builtin_amdgcn_mfma_f32_16x16x32_bf16(af[mr], bfr[nr], acc[mr][nr], 0, 0, 0);
    __builtin_amdgcn_s_setprio(0);
  };

  stage(0, 0);
  asm volatile("s_waitcnt vmcnt(0)" ::: "memory");
  __syncthreads();
  const int NT = K / 32;
  for (int kt = 0; kt < NT; kt++){
    int cur = kt & 1;
    if (kt + 1 < NT) stage(cur ^ 1, kt + 1);
    compute(cur);
    asm volatile("s_waitcnt vmcnt(0)" ::: "memory");
    __syncthreads();
  }

  #pragma unroll
  for (int nr = 0; nr < 4; nr++){
    int col = (int)n0 + wn*64 + nr*16 + rl;
    float bv = bias[col];
    #pragma unroll
    for (int mr = 0; mr < 4; mr++){
      int rowb = (int)m0 + wm*64 + mr*16 + gr*4;
      #pragma unroll
      for (int r = 0; r < 4; r++){
        int row = rowb + r;
        float v = acc[mr][nr][r] + bv;
        if (mode == 2){
          outF[(size_t)row * N + col] = v;
        } else if (mode == 0){
          int b = row >> 11, s = row & 2047, h = col >> 7, d = col & 127;
          outU0[(((size_t)(b*16 + h)) * 2048 + s) * 128 + d] = f32_bf16(v);
        } else {
          int b = row >> 11, s = row & 2047, g = col >> 8, c = col & 255;
          u16* dst = (c < 128) ? outU0 : outU1;
          dst[(((size_t)(b*4 + g)) * 2048 + s) * 128 + (c & 127)] = f32_bf16(v);
        }
      }
    }
  }
}

// ---------------- flash attention ----------------
// grid (S/64, B*H), 256 thr; each wave owns 16 q-rows, loops 64-key tiles.
// Swapped QK^T: S^T = mfma(K, Q) so per-q softmax stats are lane-local (q = l&15).
// K/V tiles staged in LDS (double-buffered, global_load_lds w16), 16B-chunk XOR
// swizzle (chunk ^= row&7) applied on the GLOBAL source (linear LDS dest, rule #21),
// matching swizzle on fragment reads -> conflict-free ds_read_b128.
__global__ __launch_bounds__(256, 2)
void attn_k(const u16* __restrict__ Q, const u16* __restrict__ Kb,
            const u16* __restrict__ VT, u16* __restrict__ O)
{
  __shared__ __align__(16) u16 sK[2][64*128];    // K tile [kv][d], swizzled
  __shared__ __align__(16) u16 sV[2][128*64];    // VT tile [d][kv], swizzled
  __shared__ __align__(16) u16 Plds[4][16*72];   // per-wave P buffer, padded stride 72
  const int t = threadIdx.x, l = t & 63, wv = t >> 6;
  const int rl = l & 15, gr = l >> 4;
  const int bh = blockIdx.y;
  const int b = bh >> 4, h = bh & 15, g = h >> 2;
  const int q0 = blockIdx.x * 64 + wv * 16;
  const u16* Qp = Q + ((size_t)(b*16 + h) * 2048 + q0) * 128;
  const u16* Kp = Kb + (size_t)(b*4 + g) * 2048 * 128;
  const u16* Vp = VT + (size_t)(b*4 + g) * 128 * 2048;   // VT[d][s]

  bf16x8 qf[4];
  #pragma unroll
  for (int ds = 0; ds < 4; ds++)
    qf[ds] = *(const bf16x8*)(Qp + rl*128 + ds*32 + gr*8);

  f32x4v acc_o[8];
  #pragma unroll
  for (int i = 0; i < 8; i++) acc_o[i] = (f32x4v)(0.0f);
  float m_run = -3.0e38f, l_run = 0.0f;
  const float scale = 0.0883883476483184f;   // 1/sqrt(128)

  // stage K[64][128] + VT[128][64] tile kt into buf, source-side swizzle
  auto stageKV = [&](int buf, int kt){
    const int kv0 = kt * 64;
    const u16* Ksrc = Kp + (size_t)kv0 * 128;   // contiguous 16KB
    #pragma unroll
    for (int j = 0; j < 4; j++){
      int n16 = j * 256 + t;        // 16B chunk index 0..1023
      int row = n16 >> 4;           // 16 chunks per 256B row
      int cl  = n16 & 15;
      int sc  = cl ^ (row & 7);
      gload16(Ksrc + row * 128 + sc * 8, &sK[buf][n16 * 8]);
    }
    const u16* Vsrc = Vp + kv0;
    #pragma unroll
    for (int j = 0; j < 4; j++){
      int n16 = j * 256 + t;
      int row = n16 >> 3;           // 8 chunks per 128B row
      int cl  = n16 & 7;
      int sc  = cl ^ (row & 7);
      gload16(Vsrc + (size_t)row * 2048 + sc * 8, &sV[buf][n16 * 8]);
    }
  };

  stageKV(0, 0);
  asm volatile("s_waitcnt vmcnt(0)" ::: "memory");
  __syncthreads();

  for (int kt = 0; kt < 32; kt++){
    const int cur = kt & 1;
    if (kt + 1 < 32) stageKV(cur ^ 1, kt + 1);
    const u16* sk = sK[cur];
    const u16* sv = sV[cur];

    float pv[4][4];
    float tm = -3.0e38f;
    #pragma unroll
    for (int tt = 0; tt < 4; tt++){
      f32x4v st = (f32x4v)(0.0f);
      bf16x8 kf[4];
      #pragma unroll
      for (int ds = 0; ds < 4; ds++){
        int r = tt*16 + rl;
        int c = ds*4 + gr;
        kf[ds] = *(const bf16x8*)(sk + r*128 + ((c ^ (r & 7)) * 8));
      }
      __builtin_amdgcn_s_setprio(1);
      #pragma unroll
      for (int ds = 0; ds < 4; ds++)
        st = __builtin_amdgcn_mfma_f32_16x16x32_bf16(kf[ds], qf[ds], st, 0, 0, 0);
      __builtin_amdgcn_s_setprio(0);
      #pragma unroll
      for (int r = 0; r < 4; r++){
        float s = st[r] * scale;
        pv[tt][r] = s;
        tm = fmaxf(tm, s);
      }
    }
    // reduce over the 4 lane-groups holding the same q (= l&15)
    tm = fmaxf(tm, __shfl_xor(tm, 16, 64));
    tm = fmaxf(tm, __shfl_xor(tm, 32, 64));
    float m_new = fmaxf(m_run, tm);
    float corr = __expf(m_run - m_new);     // exp(-inf)=0 on first tile
    float psum = 0.f;
    #pragma unroll
    for (int tt = 0; tt < 4; tt++)
      #pragma unroll
      for (int r = 0; r < 4; r++){
        float p = __expf(pv[tt][r] - m_new);
        pv[tt][r] = p;
        psum += p;
      }
    psum += __shfl_xor(psum, 16, 64);
    psum += __shfl_xor(psum, 32, 64);
    l_run = l_run * corr + psum;
    m_run = m_new;
    // rescale O: O-rows are q=(gr*4+r); fetch corr from lane q (which has l&15==q)
    float cr0 = __shfl(corr, gr*4 + 0, 64);
    float cr1 = __shfl(corr, gr*4 + 1, 64);
    float cr2 = __shfl(corr, gr*4 + 2, 64);
    float cr3 = __shfl(corr, gr*4 + 3, 64);
    #pragma unroll
    for (int dc = 0; dc < 8; dc++){
      acc_o[dc][0] *= cr0; acc_o[dc][1] *= cr1; acc_o[dc][2] *= cr2; acc_o[dc][3] *= cr3;
    }
    // P (S^T layout) -> LDS as P[q][kv] bf16, then re-read as A-fragments
    #pragma unroll
    for (int tt = 0; tt < 4; tt++){
      ushort4 pk;
      pk.x = f32_bf16(pv[tt][0]); pk.y = f32_bf16(pv[tt][1]);
      pk.z = f32_bf16(pv[tt][2]); pk.w = f32_bf16(pv[tt][3]);
      *(ushort4*)&Plds[wv][rl*72 + tt*16 + gr*4] = pk;
    }
    asm volatile("s_waitcnt lgkmcnt(0)" ::: "memory");
    #pragma unroll
    for (int kc = 0; kc < 2; kc++){
      bf16x8 pa = *(const bf16x8*)&Plds[wv][rl*72 + kc*32 + gr*8];
      bf16x8 vf[8];
      #pragma unroll
      for (int dc = 0; dc < 8; dc++){
        int r = dc*16 + rl;
        int c = kc*4 + gr;
        vf[dc] = *(const bf16x8*)(sv + r*64 + ((c ^ (r & 7)) * 8));
      }
      __builtin_amdgcn_s_setprio(1);
      #pragma unroll
      for (int dc = 0; dc < 8; dc++)
        acc_o[dc] = __builtin_amdgcn_mfma_f32_16x16x32_bf16(pa, vf[dc], acc_o[dc], 0, 0, 0);
      __builtin_amdgcn_s_setprio(0);
    }
    asm volatile("s_waitcnt vmcnt(0)" ::: "memory");
    __syncthreads();
  }
  float linv = 1.0f / l_run;
  float lr0 = __shfl(linv, gr*4 + 0, 64);
  float lr1 = __shfl(linv, gr*4 + 1, 64);
  float lr2 = __shfl(linv, gr*4 + 2, 64);
  float lr3 = __shfl(linv, gr*4 + 3, 64);
  float lrr[4] = {lr0, lr1, lr2, lr3};
  #pragma unroll
  for (int dc = 0; dc < 8; dc++)
    #pragma unroll
    for (int r = 0; r < 4; r++){
      size_t idx = ((size_t)b * 2048 + q0 + gr*4 + r) * 2048 + h*128 + dc*16 + rl;
      O[idx] = f32_bf16(acc_o[dc][r] * lrr[r]);
    }
}

extern "C" void kernel_launch(void* const* d_in, const int* in_sizes, int n_in,
                              void* d_out, int out_size, void* d_ws, size_t ws_size,
                              hipStream_t stream)
{
  const float* x   = (const float*)d_in[0];
  const float* Wq  = (const float*)d_in[1];
  const float* bq  = (const float*)d_in[2];
  const float* Wkv = (const float*)d_in[3];
  const float* bkv = (const float*)d_in[4];
  const float* Wo  = (const float*)d_in[5];
  const float* bo  = (const float*)d_in[6];
  float* out = (float*)d_out;

  char* ws = (char*)d_ws;
  size_t off = 0;
  auto alloc = [&](size_t bytes){ void* p = ws + off; off = (off + bytes + 255) & ~(size_t)255; return p; };
  u16* xb   = (u16*)alloc(8388608ull * 2);   // x bf16 [4096][2048]
  u16* WqT  = (u16*)alloc(4194304ull * 2);   // [2048][2048]
  u16* WkvT = (u16*)alloc(2097152ull * 2);   // [1024][2048]
  u16* WoT  = (u16*)alloc(4194304ull * 2);   // [2048][2048]
  u16* Qb   = (u16*)alloc(8388608ull * 2);   // [B,H,S,D]
  u16* Kb   = (u16*)alloc(2097152ull * 2);   // [B,G,S,D]
  u16* Vb   = (u16*)alloc(2097152ull * 2);   // [B,G,S,D]
  u16* VTb  = (u16*)alloc(2097152ull * 2);   // [B,G,D,S]
  u16* Ob   = (u16*)alloc(8388608ull * 2);   // [B,S,E]

  cvt_f32_bf16_k<<<4096, 256, 0, stream>>>(x, xb, 8388608);
  transpose_cvt_k<float><<<dim3(32, 32, 1), 256, 0, stream>>>(Wq,  WqT,  2048, 2048);
  transpose_cvt_k<float><<<dim3(16, 32, 1), 256, 0, stream>>>(Wkv, WkvT, 2048, 1024);
  transpose_cvt_k<float><<<dim3(32, 32, 1), 256, 0, stream>>>(Wo,  WoT,  2048, 2048);

  gemm_bf16_k<<<dim3(32, 16), 256, 0, stream>>>(xb, WqT,  bq,  Qb, nullptr, nullptr, 4096, 2048, 2048, 0);
  gemm_bf16_k<<<dim3(32, 8),  256, 0, stream>>>(xb, WkvT, bkv, Kb, Vb,      nullptr, 4096, 1024, 2048, 1);

  transpose_cvt_k<u16><<<dim3(2, 32, 8), 256, 0, stream>>>(Vb, VTb, 2048, 128);

  attn_k<<<dim3(32, 32), 256, 0, stream>>>(Qb, Kb, VTb, Ob);

  gemm_bf16_k<<<dim3(32, 16), 256, 0, stream>>>(Ob, WoT, bo, nullptr, nullptr, out, 4096, 2048, 2048, 2);
}

// Round 4
// 354.228 us; speedup vs baseline: 2.0291x; 1.1038x over previous
//
#include <hip/hip_runtime.h>

#define DEV __device__ __forceinline__

typedef unsigned short u16;
typedef unsigned int u32;
using bf16x8 = __attribute__((ext_vector_type(8))) __bf16;
using f32x4v = __attribute__((ext_vector_type(4))) float;

typedef __attribute__((address_space(1))) void gas_void;
typedef __attribute__((address_space(3))) void las_void;

DEV u16 f32_bf16(float f){
  u32 u = __float_as_uint(f);
  u += 0x7FFFu + ((u >> 16) & 1u);   // RNE
  return (u16)(u >> 16);
}
DEV float bf16_f32(u16 h){ return __uint_as_float(((u32)h) << 16); }

DEV void gload16(const void* g, void* l){
  __builtin_amdgcn_global_load_lds((gas_void*)g, (las_void*)l, 16, 0, 0);
}

DEV float exp2_hw(float x){
  float r;
  asm("v_exp_f32 %0, %1" : "=v"(r) : "v"(x));
  return r;
}

// Q is pre-scaled by (1/sqrt(128)) * log2(e) in the QKV GEMM epilogue,
// so attention uses exp2 directly (exact softmax in base-2 space).
#define QSCL 0.12752333f

// ---------------- prep: x f32 -> bf16 ----------------
__global__ void cvt_f32_bf16_k(const float* __restrict__ in, u16* __restrict__ out, int n){
  int i = (blockIdx.x * 256 + threadIdx.x) * 8;
  if (i >= n) return;
  float4 a = *(const float4*)(in + i);
  float4 b = *(const float4*)(in + i + 4);
  uint4 r;
  r.x = (u32)f32_bf16(a.x) | ((u32)f32_bf16(a.y) << 16);
  r.y = (u32)f32_bf16(a.z) | ((u32)f32_bf16(a.w) << 16);
  r.z = (u32)f32_bf16(b.x) | ((u32)f32_bf16(b.y) << 16);
  r.w = (u32)f32_bf16(b.z) | ((u32)f32_bf16(b.w) << 16);
  *(uint4*)(out + i) = r;
}

// ------------- prep: transpose+convert, out[c][r] = in[r][c] -------------
template<typename T>
__global__ void transpose_cvt_k(const T* __restrict__ in, u16* __restrict__ out, int R, int C){
  in  += (size_t)blockIdx.z * R * C;
  out += (size_t)blockIdx.z * R * C;
  __shared__ float tile[64][65];
  int c0 = blockIdx.x * 64, r0 = blockIdx.y * 64;
  int t = threadIdx.x;
  int lr = t >> 4;         // 0..15
  int lc = (t & 15) * 4;   // 0..60
  #pragma unroll
  for (int p = 0; p < 4; p++){
    int row = p * 16 + lr;
    const T* src = in + (size_t)(r0 + row) * C + c0 + lc;
    float v0, v1, v2, v3;
    if constexpr (sizeof(T) == 4){
      float4 v = *(const float4*)src;
      v0 = v.x; v1 = v.y; v2 = v.z; v3 = v.w;
    } else {
      ushort4 v = *(const ushort4*)src;
      v0 = bf16_f32(v.x); v1 = bf16_f32(v.y); v2 = bf16_f32(v.z); v3 = bf16_f32(v.w);
    }
    tile[row][lc+0] = v0; tile[row][lc+1] = v1; tile[row][lc+2] = v2; tile[row][lc+3] = v3;
  }
  __syncthreads();
  #pragma unroll
  for (int p = 0; p < 4; p++){
    int ocol = p * 16 + lr;
    ushort4 w;
    w.x = f32_bf16(tile[lc+0][ocol]);
    w.y = f32_bf16(tile[lc+1][ocol]);
    w.z = f32_bf16(tile[lc+2][ocol]);
    w.w = f32_bf16(tile[lc+3][ocol]);
    *(ushort4*)(out + (size_t)(c0 + ocol) * R + r0 + lc) = w;
  }
}

// ---------------- 256x256 deep-pipelined GEMM ----------------
// C[m][n] = sum_k A[m][k]*BT[n][k] + bias[n].  M=4096 via grid, BK=32, 512 thr
// (8 waves 2Mx4N, each owns 128x64 = 8x4 frags of 16x16x32).
// FOUR LDS K-tile buffers; stage tile t+2 while computing t; s_waitcnt vmcnt(4)
// (counted, never 0 until tail) + raw s_barrier -> loads stay in flight across
// barriers (T4). LDS reads conflict-free via 16B-chunk ^= (row>>1)&3 swizzle,
// applied as inverse swizzle on the GLOBAL source (linear gload_lds dest).
// mode 0: merged QKV epilogue (bf16 Q*QSCL / K / V scatter); mode 2: f32 out.
__global__ __launch_bounds__(512, 2)
void gemm256_k(const u16* __restrict__ A, const u16* __restrict__ BT,
               const float* __restrict__ bias0, const float* __restrict__ bias1,
               u16* __restrict__ outQ, u16* __restrict__ outK, u16* __restrict__ outV,
               float* __restrict__ outF, int K, int mode)
{
  __shared__ __align__(16) u16 sA[4][256*32];
  __shared__ __align__(16) u16 sB[4][256*32];
  const int t = threadIdx.x;
  const int l = t & 63, wv = t >> 6;
  const int wm = wv >> 2, wn = wv & 3;
  const int rl = l & 15, gr = l >> 4;
  const size_t m0 = (size_t)blockIdx.x * 256, n0 = (size_t)blockIdx.y * 256;
  const u16* gA = A + m0 * K;
  const u16* gB = BT + n0 * K;

  // staging: thread t covers 16B chunks {t, t+512} of each 16KB tile
  const u16* gAs[2]; const u16* gBs[2]; int ldso[2];
  #pragma unroll
  for (int j = 0; j < 2; j++){
    int c = t + j * 512;
    int row = c >> 2, cl = c & 3;
    int clp = cl ^ ((row >> 1) & 3);          // inverse swizzle on source
    gAs[j] = gA + (size_t)row * K + clp * 8;
    gBs[j] = gB + (size_t)row * K + clp * 8;
    ldso[j] = c * 8;
  }
  auto stage = [&](int kt){
    int buf = kt & 3;
    int k0 = kt * 32;
    #pragma unroll
    for (int j = 0; j < 2; j++){
      gload16(gAs[j] + k0, &sA[buf][ldso[j]]);
      gload16(gBs[j] + k0, &sB[buf][ldso[j]]);
    }
  };

  // per-lane fragment read offsets (swizzled chunk = gr ^ ((rl>>1)&3))
  const int swz8 = (gr ^ ((rl >> 1) & 3)) * 8;
  int offA[8], offB[4];
  #pragma unroll
  for (int mr = 0; mr < 8; mr++) offA[mr] = (wm*128 + mr*16 + rl) * 32 + swz8;
  #pragma unroll
  for (int nr = 0; nr < 4; nr++) offB[nr] = (wn*64 + nr*16 + rl) * 32 + swz8;

  f32x4v acc[8][4];
  #pragma unroll
  for (int i = 0; i < 8; i++)
    #pragma unroll
    for (int j = 0; j < 4; j++)
      acc[i][j] = (f32x4v)(0.0f);

  const int NT = K / 32;
  stage(0); stage(1);
  asm volatile("s_waitcnt vmcnt(4)" ::: "memory");
  __builtin_amdgcn_s_barrier();

  for (int kt = 0; kt < NT; kt++){
    const u16* sa = sA[kt & 3];
    const u16* sb = sB[kt & 3];
    bf16x8 af[8], bfr[4];
    #pragma unroll
    for (int mr = 0; mr < 8; mr++) af[mr] = *(const bf16x8*)(sa + offA[mr]);
    #pragma unroll
    for (int nr = 0; nr < 4; nr++) bfr[nr] = *(const bf16x8*)(sb + offB[nr]);
    if (kt + 2 < NT){
      stage(kt + 2);
      asm volatile("s_waitcnt vmcnt(4)" ::: "memory");
    } else {
      asm volatile("s_waitcnt vmcnt(0)" ::: "memory");
    }
    __builtin_amdgcn_s_barrier();
    __builtin_amdgcn_s_setprio(1);
    #pragma unroll
    for (int mr = 0; mr < 8; mr++)
      #pragma unroll
      for (int nr = 0; nr < 4; nr++)
        acc[mr][nr] = __builtin_amdgcn_mfma_f32_16x16x32_bf16(af[mr], bfr[nr], acc[mr][nr], 0, 0, 0);
    __builtin_amdgcn_s_setprio(0);
  }

  #pragma unroll
  for (int nr = 0; nr < 4; nr++){
    int col = (int)n0 + wn*64 + nr*16 + rl;
    float bv = (mode == 2 || col < 2048) ? bias0[col < 2048 ? col : 0] : 0.0f;
    if (mode != 2 && col >= 2048) bv = bias1[col - 2048];
    #pragma unroll
    for (int mr = 0; mr < 8; mr++){
      int rowb = (int)m0 + wm*128 + mr*16 + gr*4;
      #pragma unroll
      for (int r = 0; r < 4; r++){
        int row = rowb + r;
        float v = acc[mr][nr][r] + bv;
        if (mode == 2){
          outF[(size_t)row * 2048 + col] = v;
        } else if (col < 2048){
          int b = row >> 11, s = row & 2047, h = col >> 7, d = col & 127;
          outQ[(((size_t)(b*16 + h)) * 2048 + s) * 128 + d] = f32_bf16(v * QSCL);
        } else {
          int b = row >> 11, s = row & 2047;
          int c2 = col - 2048, g = c2 >> 8, cc = c2 & 255;
          u16* dst = (cc < 128) ? outK : outV;
          dst[(((size_t)(b*4 + g)) * 2048 + s) * 128 + (cc & 127)] = f32_bf16(v);
        }
      }
    }
  }
}

// ---------------- flash attention ----------------
// grid (S/64, B*H), 256 thr; each wave owns 16 q-rows, loops 64-key tiles.
// Swapped QK^T (S^T = mfma(K,Q)) -> per-q stats lane-local. Q pre-scaled by
// QSCL so p = exp2(s - m) exactly. T13 defer-max skips O-rescale when max
// growth <= 11 (log2-space). K/V double-buffered in LDS via gload_lds.
__global__ __launch_bounds__(256, 2)
void attn_k(const u16* __restrict__ Q, const u16* __restrict__ Kb,
            const u16* __restrict__ VT, u16* __restrict__ O)
{
  __shared__ __align__(16) u16 sK[2][64*128];    // K tile [kv][d], swizzled
  __shared__ __align__(16) u16 sV[2][128*64];    // VT tile [d][kv], swizzled
  __shared__ __align__(16) u16 Plds[4][16*72];   // per-wave P buffer, padded
  const int t = threadIdx.x, l = t & 63, wv = t >> 6;
  const int rl = l & 15, gr = l >> 4;
  const int bh = blockIdx.y;
  const int b = bh >> 4, h = bh & 15, g = h >> 2;
  const int q0 = blockIdx.x * 64 + wv * 16;
  const u16* Qp = Q + ((size_t)(b*16 + h) * 2048 + q0) * 128;
  const u16* Kp = Kb + (size_t)(b*4 + g) * 2048 * 128;
  const u16* Vp = VT + (size_t)(b*4 + g) * 128 * 2048;   // VT[d][s]

  bf16x8 qf[4];
  #pragma unroll
  for (int ds = 0; ds < 4; ds++)
    qf[ds] = *(const bf16x8*)(Qp + rl*128 + ds*32 + gr*8);

  f32x4v acc_o[8];
  #pragma unroll
  for (int i = 0; i < 8; i++) acc_o[i] = (f32x4v)(0.0f);
  float m_run = -3.0e38f, l_run = 0.0f;

  auto stageKV = [&](int buf, int kt){
    const int kv0 = kt * 64;
    const u16* Ksrc = Kp + (size_t)kv0 * 128;
    #pragma unroll
    for (int j = 0; j < 4; j++){
      int n16 = j * 256 + t;
      int row = n16 >> 4, cl = n16 & 15;
      int sc = cl ^ (row & 7);
      gload16(Ksrc + row * 128 + sc * 8, &sK[buf][n16 * 8]);
    }
    const u16* Vsrc = Vp + kv0;
    #pragma unroll
    for (int j = 0; j < 4; j++){
      int n16 = j * 256 + t;
      int row = n16 >> 3, cl = n16 & 7;
      int sc = cl ^ (row & 7);
      gload16(Vsrc + (size_t)row * 2048 + sc * 8, &sV[buf][n16 * 8]);
    }
  };

  stageKV(0, 0);
  asm volatile("s_waitcnt vmcnt(0)" ::: "memory");
  __syncthreads();

  for (int kt = 0; kt < 32; kt++){
    const int cur = kt & 1;
    if (kt + 1 < 32) stageKV(cur ^ 1, kt + 1);
    const u16* sk = sK[cur];
    const u16* sv = sV[cur];

    float pv[4][4];
    float tm = -3.0e38f;
    #pragma unroll
    for (int tt = 0; tt < 4; tt++){
      f32x4v st = (f32x4v)(0.0f);
      bf16x8 kf[4];
      #pragma unroll
      for (int ds = 0; ds < 4; ds++){
        int r = tt*16 + rl;
        int c = ds*4 + gr;
        kf[ds] = *(const bf16x8*)(sk + r*128 + ((c ^ (r & 7)) * 8));
      }
      __builtin_amdgcn_s_setprio(1);
      #pragma unroll
      for (int ds = 0; ds < 4; ds++)
        st = __builtin_amdgcn_mfma_f32_16x16x32_bf16(kf[ds], qf[ds], st, 0, 0, 0);
      __builtin_amdgcn_s_setprio(0);
      #pragma unroll
      for (int r = 0; r < 4; r++){
        pv[tt][r] = st[r];
        tm = fmaxf(tm, st[r]);
      }
    }
    tm = fmaxf(tm, __shfl_xor(tm, 16, 64));
    tm = fmaxf(tm, __shfl_xor(tm, 32, 64));
    // T13 defer-max: only rescale when the max grew materially
    if (!__all(tm <= m_run + 11.0f)){
      float m_new = fmaxf(m_run, tm);
      float corr = exp2_hw(m_run - m_new);   // 0 on first tile
      l_run *= corr;
      float cr0 = __shfl(corr, gr*4 + 0, 64);
      float cr1 = __shfl(corr, gr*4 + 1, 64);
      float cr2 = __shfl(corr, gr*4 + 2, 64);
      float cr3 = __shfl(corr, gr*4 + 3, 64);
      #pragma unroll
      for (int dc = 0; dc < 8; dc++){
        acc_o[dc][0] *= cr0; acc_o[dc][1] *= cr1; acc_o[dc][2] *= cr2; acc_o[dc][3] *= cr3;
      }
      m_run = m_new;
    }
    float psum = 0.f;
    #pragma unroll
    for (int tt = 0; tt < 4; tt++)
      #pragma unroll
      for (int r = 0; r < 4; r++){
        float p = exp2_hw(pv[tt][r] - m_run);
        pv[tt][r] = p;
        psum += p;
      }
    psum += __shfl_xor(psum, 16, 64);
    psum += __shfl_xor(psum, 32, 64);
    l_run += psum;

    #pragma unroll
    for (int tt = 0; tt < 4; tt++){
      ushort4 pk;
      pk.x = f32_bf16(pv[tt][0]); pk.y = f32_bf16(pv[tt][1]);
      pk.z = f32_bf16(pv[tt][2]); pk.w = f32_bf16(pv[tt][3]);
      *(ushort4*)&Plds[wv][rl*72 + tt*16 + gr*4] = pk;
    }
    asm volatile("s_waitcnt lgkmcnt(0)" ::: "memory");
    #pragma unroll
    for (int kc = 0; kc < 2; kc++){
      bf16x8 pa = *(const bf16x8*)&Plds[wv][rl*72 + kc*32 + gr*8];
      bf16x8 vf[8];
      #pragma unroll
      for (int dc = 0; dc < 8; dc++){
        int r = dc*16 + rl;
        int c = kc*4 + gr;
        vf[dc] = *(const bf16x8*)(sv + r*64 + ((c ^ (r & 7)) * 8));
      }
      __builtin_amdgcn_s_setprio(1);
      #pragma unroll
      for (int dc = 0; dc < 8; dc++)
        acc_o[dc] = __builtin_amdgcn_mfma_f32_16x16x32_bf16(pa, vf[dc], acc_o[dc], 0, 0, 0);
      __builtin_amdgcn_s_setprio(0);
    }
    asm volatile("s_waitcnt vmcnt(0)" ::: "memory");
    __syncthreads();
  }
  float linv = 1.0f / l_run;
  float lr0 = __shfl(linv, gr*4 + 0, 64);
  float lr1 = __shfl(linv, gr*4 + 1, 64);
  float lr2 = __shfl(linv, gr*4 + 2, 64);
  float lr3 = __shfl(linv, gr*4 + 3, 64);
  float lrr[4] = {lr0, lr1, lr2, lr3};
  #pragma unroll
  for (int dc = 0; dc < 8; dc++)
    #pragma unroll
    for (int r = 0; r < 4; r++){
      size_t idx = ((size_t)b * 2048 + q0 + gr*4 + r) * 2048 + h*128 + dc*16 + rl;
      O[idx] = f32_bf16(acc_o[dc][r] * lrr[r]);
    }
}

extern "C" void kernel_launch(void* const* d_in, const int* in_sizes, int n_in,
                              void* d_out, int out_size, void* d_ws, size_t ws_size,
                              hipStream_t stream)
{
  const float* x   = (const float*)d_in[0];
  const float* Wq  = (const float*)d_in[1];
  const float* bq  = (const float*)d_in[2];
  const float* Wkv = (const float*)d_in[3];
  const float* bkv = (const float*)d_in[4];
  const float* Wo  = (const float*)d_in[5];
  const float* bo  = (const float*)d_in[6];
  float* out = (float*)d_out;

  char* ws = (char*)d_ws;
  size_t off = 0;
  auto alloc = [&](size_t bytes){ void* p = ws + off; off = (off + bytes + 255) & ~(size_t)255; return p; };
  u16* xb     = (u16*)alloc(8388608ull * 2);   // x bf16 [4096][2048]
  u16* WqkvT  = (u16*)alloc(6291456ull * 2);   // [3072][2048]  (rows: Wq cols, then Wkv cols)
  u16* WoT    = (u16*)alloc(4194304ull * 2);   // [2048][2048]
  u16* Qb     = (u16*)alloc(8388608ull * 2);   // [B,H,S,D]
  u16* Kb     = (u16*)alloc(2097152ull * 2);   // [B,G,S,D]
  u16* Vb     = (u16*)alloc(2097152ull * 2);   // [B,G,S,D]
  u16* VTb    = (u16*)alloc(2097152ull * 2);   // [B,G,D,S]
  u16* Ob     = (u16*)alloc(8388608ull * 2);   // [B,S,E]

  cvt_f32_bf16_k<<<4096, 256, 0, stream>>>(x, xb, 8388608);
  transpose_cvt_k<float><<<dim3(32, 32, 1), 256, 0, stream>>>(Wq,  WqkvT, 2048, 2048);
  transpose_cvt_k<float><<<dim3(16, 32, 1), 256, 0, stream>>>(Wkv, WqkvT + 2048ull*2048ull, 2048, 1024);
  transpose_cvt_k<float><<<dim3(32, 32, 1), 256, 0, stream>>>(Wo,  WoT, 2048, 2048);

  // merged QKV projection: [4096,2048] x [2048,3072]
  gemm256_k<<<dim3(16, 12), 512, 0, stream>>>(xb, WqkvT, bq, bkv, Qb, Kb, Vb, nullptr, 2048, 0);

  transpose_cvt_k<u16><<<dim3(2, 32, 8), 256, 0, stream>>>(Vb, VTb, 2048, 128);

  attn_k<<<dim3(32, 32), 256, 0, stream>>>(Qb, Kb, VTb, Ob);

  // output projection: [4096,2048] x [2048,2048] -> f32
  gemm256_k<<<dim3(16, 8), 512, 0, stream>>>(Ob, WoT, bo, nullptr, nullptr, nullptr, nullptr, out, 2048, 2);
}

// Round 5
// 314.822 us; speedup vs baseline: 2.2831x; 1.1252x over previous
//
#include <hip/hip_runtime.h>

#define DEV __device__ __forceinline__

typedef unsigned short u16;
typedef unsigned int u32;
using bf16x8 = __attribute__((ext_vector_type(8))) __bf16;
using f32x4v = __attribute__((ext_vector_type(4))) float;
using f32x16 = __attribute__((ext_vector_type(16))) float;

typedef __attribute__((address_space(1))) void gas_void;
typedef __attribute__((address_space(3))) void las_void;

DEV u16 f32_bf16(float f){
  u32 u = __float_as_uint(f);
  u += 0x7FFFu + ((u >> 16) & 1u);   // RNE
  return (u16)(u >> 16);
}
DEV float bf16_f32(u16 h){ return __uint_as_float(((u32)h) << 16); }

DEV void gload16(const void* g, void* l){
  __builtin_amdgcn_global_load_lds((gas_void*)g, (las_void*)l, 16, 0, 0);
}

DEV float exp2_hw(float x){
  float r;
  asm("v_exp_f32 %0, %1" : "=v"(r) : "v"(x));
  return r;
}
DEV u32 cvtpk_bf16(float lo, float hi){
  u32 r;
  asm("v_cvt_pk_bf16_f32 %0, %1, %2" : "=v"(r) : "v"(lo), "v"(hi));
  return r;
}
DEV bf16x8 mk_bf16x8(u32 a, u32 b, u32 c, u32 d){
  union { u32 w[4]; bf16x8 v; } u;
  u.w[0] = a; u.w[1] = b; u.w[2] = c; u.w[3] = d;
  return u.v;
}

// Q is pre-scaled by (1/sqrt(128)) * log2(e) in the QKV GEMM epilogue,
// so attention uses exp2 directly (exact softmax in base-2 space).
#define QSCL 0.12752333f

// ---------------- prep: x f32 -> bf16 ----------------
__global__ void cvt_f32_bf16_k(const float* __restrict__ in, u16* __restrict__ out, int n){
  int i = (blockIdx.x * 256 + threadIdx.x) * 8;
  if (i >= n) return;
  float4 a = *(const float4*)(in + i);
  float4 b = *(const float4*)(in + i + 4);
  uint4 r;
  r.x = (u32)f32_bf16(a.x) | ((u32)f32_bf16(a.y) << 16);
  r.y = (u32)f32_bf16(a.z) | ((u32)f32_bf16(a.w) << 16);
  r.z = (u32)f32_bf16(b.x) | ((u32)f32_bf16(b.y) << 16);
  r.w = (u32)f32_bf16(b.z) | ((u32)f32_bf16(b.w) << 16);
  *(uint4*)(out + i) = r;
}

// ------------- prep: transpose+convert, out[c][r] = in[r][c] -------------
template<typename T>
__global__ void transpose_cvt_k(const T* __restrict__ in, u16* __restrict__ out, int R, int C){
  in  += (size_t)blockIdx.z * R * C;
  out += (size_t)blockIdx.z * R * C;
  __shared__ float tile[64][65];
  int c0 = blockIdx.x * 64, r0 = blockIdx.y * 64;
  int t = threadIdx.x;
  int lr = t >> 4;         // 0..15
  int lc = (t & 15) * 4;   // 0..60
  #pragma unroll
  for (int p = 0; p < 4; p++){
    int row = p * 16 + lr;
    const T* src = in + (size_t)(r0 + row) * C + c0 + lc;
    float v0, v1, v2, v3;
    if constexpr (sizeof(T) == 4){
      float4 v = *(const float4*)src;
      v0 = v.x; v1 = v.y; v2 = v.z; v3 = v.w;
    } else {
      ushort4 v = *(const ushort4*)src;
      v0 = bf16_f32(v.x); v1 = bf16_f32(v.y); v2 = bf16_f32(v.z); v3 = bf16_f32(v.w);
    }
    tile[row][lc+0] = v0; tile[row][lc+1] = v1; tile[row][lc+2] = v2; tile[row][lc+3] = v3;
  }
  __syncthreads();
  #pragma unroll
  for (int p = 0; p < 4; p++){
    int ocol = p * 16 + lr;
    ushort4 w;
    w.x = f32_bf16(tile[lc+0][ocol]);
    w.y = f32_bf16(tile[lc+1][ocol]);
    w.z = f32_bf16(tile[lc+2][ocol]);
    w.w = f32_bf16(tile[lc+3][ocol]);
    *(ushort4*)(out + (size_t)(c0 + ocol) * R + r0 + lc) = w;
  }
}

// ---------------- 256x256 deep-pipelined GEMM (QKV) ----------------
// C[m][n] = sum_k A[m][k]*BT[n][k] + bias[n].  BK=32, 512 thr, 8 waves 2Mx4N.
// 4 LDS K-tile buffers, lookahead-2, counted vmcnt(4) + raw s_barrier.
// Epilogue: Q*QSCL -> Q[B,H,S,D]; K -> [B,G,S,D]; V -> VT[B,G,D,S] (ushort4).
__global__ __launch_bounds__(512, 2)
void gemm256_k(const u16* __restrict__ A, const u16* __restrict__ BT,
               const float* __restrict__ bias0, const float* __restrict__ bias1,
               u16* __restrict__ outQ, u16* __restrict__ outK, u16* __restrict__ outVT,
               int K)
{
  __shared__ __align__(16) u16 sA[4][256*32];
  __shared__ __align__(16) u16 sB[4][256*32];
  const int t = threadIdx.x;
  const int l = t & 63, wv = t >> 6;
  const int wm = wv >> 2, wn = wv & 3;
  const int rl = l & 15, gr = l >> 4;
  const size_t m0 = (size_t)blockIdx.x * 256, n0 = (size_t)blockIdx.y * 256;
  const u16* gA = A + m0 * K;
  const u16* gB = BT + n0 * K;

  const u16* gAs[2]; const u16* gBs[2]; int ldso[2];
  #pragma unroll
  for (int j = 0; j < 2; j++){
    int c = t + j * 512;
    int row = c >> 2, cl = c & 3;
    int clp = cl ^ ((row >> 1) & 3);          // inverse swizzle on source
    gAs[j] = gA + (size_t)row * K + clp * 8;
    gBs[j] = gB + (size_t)row * K + clp * 8;
    ldso[j] = c * 8;
  }
  auto stage = [&](int kt){
    int buf = kt & 3;
    int k0 = kt * 32;
    #pragma unroll
    for (int j = 0; j < 2; j++){
      gload16(gAs[j] + k0, &sA[buf][ldso[j]]);
      gload16(gBs[j] + k0, &sB[buf][ldso[j]]);
    }
  };

  const int swz8 = (gr ^ ((rl >> 1) & 3)) * 8;
  int offA[8], offB[4];
  #pragma unroll
  for (int mr = 0; mr < 8; mr++) offA[mr] = (wm*128 + mr*16 + rl) * 32 + swz8;
  #pragma unroll
  for (int nr = 0; nr < 4; nr++) offB[nr] = (wn*64 + nr*16 + rl) * 32 + swz8;

  f32x4v acc[8][4];
  #pragma unroll
  for (int i = 0; i < 8; i++)
    #pragma unroll
    for (int j = 0; j < 4; j++)
      acc[i][j] = (f32x4v)(0.0f);

  const int NT = K / 32;
  stage(0); stage(1);
  asm volatile("s_waitcnt vmcnt(4)" ::: "memory");
  __builtin_amdgcn_s_barrier();

  for (int kt = 0; kt < NT; kt++){
    const u16* sa = sA[kt & 3];
    const u16* sb = sB[kt & 3];
    bf16x8 af[8], bfr[4];
    #pragma unroll
    for (int mr = 0; mr < 8; mr++) af[mr] = *(const bf16x8*)(sa + offA[mr]);
    #pragma unroll
    for (int nr = 0; nr < 4; nr++) bfr[nr] = *(const bf16x8*)(sb + offB[nr]);
    if (kt + 2 < NT){
      stage(kt + 2);
      asm volatile("s_waitcnt vmcnt(4)" ::: "memory");
    } else {
      asm volatile("s_waitcnt vmcnt(0)" ::: "memory");
    }
    __builtin_amdgcn_s_barrier();
    __builtin_amdgcn_s_setprio(1);
    #pragma unroll
    for (int mr = 0; mr < 8; mr++)
      #pragma unroll
      for (int nr = 0; nr < 4; nr++)
        acc[mr][nr] = __builtin_amdgcn_mfma_f32_16x16x32_bf16(af[mr], bfr[nr], acc[mr][nr], 0, 0, 0);
    __builtin_amdgcn_s_setprio(0);
  }

  #pragma unroll
  for (int nr = 0; nr < 4; nr++){
    int col = (int)n0 + wn*64 + nr*16 + rl;
    float bv = (col < 2048) ? bias0[col] : bias1[col - 2048];
    #pragma unroll
    for (int mr = 0; mr < 8; mr++){
      int rowb = (int)m0 + wm*128 + mr*16 + gr*4;
      int b = rowb >> 11, s0 = rowb & 2047;
      if (col < 2048){
        int h = col >> 7, d = col & 127;
        #pragma unroll
        for (int r = 0; r < 4; r++)
          outQ[(((size_t)(b*16 + h)) * 2048 + s0 + r) * 128 + d] =
            f32_bf16((acc[mr][nr][r] + bv) * QSCL);
      } else {
        int c2 = col - 2048, g = c2 >> 8, cc = c2 & 255;
        if (cc < 128){
          #pragma unroll
          for (int r = 0; r < 4; r++)
            outK[(((size_t)(b*4 + g)) * 2048 + s0 + r) * 128 + cc] =
              f32_bf16(acc[mr][nr][r] + bv);
        } else {
          int d = cc - 128;
          ushort4 w;
          w.x = f32_bf16(acc[mr][nr][0] + bv);
          w.y = f32_bf16(acc[mr][nr][1] + bv);
          w.z = f32_bf16(acc[mr][nr][2] + bv);
          w.w = f32_bf16(acc[mr][nr][3] + bv);
          *(ushort4*)&outVT[(((size_t)(b*4 + g)) * 128 + d) * 2048 + s0] = w;
        }
      }
    }
  }
}

// ---------------- 256x128 deep-pipelined GEMM (O-proj, full-fill grid) ------
__global__ __launch_bounds__(512, 2)
void gemm_o_k(const u16* __restrict__ A, const u16* __restrict__ BT,
              const float* __restrict__ bias, float* __restrict__ outF, int K)
{
  __shared__ __align__(16) u16 sA[4][256*32];
  __shared__ __align__(16) u16 sB[4][128*32];
  const int t = threadIdx.x;
  const int l = t & 63, wv = t >> 6;
  const int wm = wv >> 2, wn = wv & 3;
  const int rl = l & 15, gr = l >> 4;
  const size_t m0 = (size_t)blockIdx.x * 256, n0 = (size_t)blockIdx.y * 128;
  const u16* gA = A + m0 * K;
  const u16* gB = BT + n0 * K;

  const u16* gAs[2]; int ldsoA[2];
  #pragma unroll
  for (int j = 0; j < 2; j++){
    int c = t + j * 512;
    int row = c >> 2, cl = c & 3;
    int clp = cl ^ ((row >> 1) & 3);
    gAs[j] = gA + (size_t)row * K + clp * 8;
    ldsoA[j] = c * 8;
  }
  const int rowB = t >> 2;
  const int clB = (t & 3) ^ ((rowB >> 1) & 3);
  const u16* gBs = gB + (size_t)rowB * K + clB * 8;
  const int ldsoB = t * 8;

  auto stage = [&](int kt){
    int buf = kt & 3;
    int k0 = kt * 32;
    gload16(gAs[0] + k0, &sA[buf][ldsoA[0]]);
    gload16(gAs[1] + k0, &sA[buf][ldsoA[1]]);
    gload16(gBs + k0, &sB[buf][ldsoB]);
  };

  const int swz8 = (gr ^ ((rl >> 1) & 3)) * 8;
  int offA[8], offB[2];
  #pragma unroll
  for (int mr = 0; mr < 8; mr++) offA[mr] = (wm*128 + mr*16 + rl) * 32 + swz8;
  #pragma unroll
  for (int nr = 0; nr < 2; nr++) offB[nr] = (wn*32 + nr*16 + rl) * 32 + swz8;

  f32x4v acc[8][2];
  #pragma unroll
  for (int i = 0; i < 8; i++)
    #pragma unroll
    for (int j = 0; j < 2; j++)
      acc[i][j] = (f32x4v)(0.0f);

  const int NT = K / 32;
  stage(0); stage(1);
  asm volatile("s_waitcnt vmcnt(3)" ::: "memory");
  __builtin_amdgcn_s_barrier();

  for (int kt = 0; kt < NT; kt++){
    const u16* sa = sA[kt & 3];
    const u16* sb = sB[kt & 3];
    bf16x8 af[8], bfr[2];
    #pragma unroll
    for (int mr = 0; mr < 8; mr++) af[mr] = *(const bf16x8*)(sa + offA[mr]);
    #pragma unroll
    for (int nr = 0; nr < 2; nr++) bfr[nr] = *(const bf16x8*)(sb + offB[nr]);
    if (kt + 2 < NT){
      stage(kt + 2);
      asm volatile("s_waitcnt vmcnt(3)" ::: "memory");
    } else {
      asm volatile("s_waitcnt vmcnt(0)" ::: "memory");
    }
    __builtin_amdgcn_s_barrier();
    __builtin_amdgcn_s_setprio(1);
    #pragma unroll
    for (int mr = 0; mr < 8; mr++)
      #pragma unroll
      for (int nr = 0; nr < 2; nr++)
        acc[mr][nr] = __builtin_amdgcn_mfma_f32_16x16x32_bf16(af[mr], bfr[nr], acc[mr][nr], 0, 0, 0);
    __builtin_amdgcn_s_setprio(0);
  }

  #pragma unroll
  for (int nr = 0; nr < 2; nr++){
    int col = (int)n0 + wn*32 + nr*16 + rl;
    float bv = bias[col];
    #pragma unroll
    for (int mr = 0; mr < 8; mr++){
      int rowb = (int)m0 + wm*128 + mr*16 + gr*4;
      #pragma unroll
      for (int r = 0; r < 4; r++)
        outF[(size_t)(rowb + r) * 2048 + col] = acc[mr][nr][r] + bv;
    }
  }
}

// ---------------- flash attention (32q/wave, 32x32x16 MFMA, in-register P) ---
// grid (S/128, B*H), 256 thr = 4 waves, each wave owns 32 q-rows; KV tile 64.
// Swapped QK^T: p = mfma(K, Q) -> S^T with col=q=lane&31, row kv via regs
// (row = (r&3)+8*(r>>2)+4*hi). Softmax stats lane-local per q (one shfl_xor 32).
// P -> bf16 PV A-frags fully in-register: cvt_pk pairs + lane l<->l+32 half
// exchange (shfl_xor 32 + select). T13 defer-max. K/V LDS double-buffered via
// global_load_lds with 16B-chunk XOR swizzle (source-side, rule #21).
__global__ __launch_bounds__(256, 2)
void attn_k(const u16* __restrict__ Q, const u16* __restrict__ Kb,
            const u16* __restrict__ VT, u16* __restrict__ O)
{
  __shared__ __align__(16) u16 sK[2][64*128];    // K tile [kv][d]
  __shared__ __align__(16) u16 sV[2][128*64];    // VT tile [d][kv]
  const int t = threadIdx.x, l = t & 63, wv = t >> 6;
  const int lq = l & 31, hi = l >> 5;
  const int bh = blockIdx.y;
  const int b = bh >> 4, h = bh & 15, g = h >> 2;
  const int q0 = blockIdx.x * 128 + wv * 32;
  const u16* Qp = Q + ((size_t)(b*16 + h) * 2048 + q0) * 128;
  const u16* Kp = Kb + (size_t)(b*4 + g) * 2048 * 128;
  const u16* Vp = VT + (size_t)(b*4 + g) * 128 * 2048;   // VT[d][s]

  // Q as B-operand: lane holds col q=lq, k-elems d = ds*16 + hi*8 + j
  bf16x8 qf[8];
  #pragma unroll
  for (int ds = 0; ds < 8; ds++)
    qf[ds] = *(const bf16x8*)(Qp + (size_t)lq*128 + ds*16 + hi*8);

  f32x16 acc[4];
  #pragma unroll
  for (int i = 0; i < 4; i++) acc[i] = (f32x16)(0.0f);
  float m_run = -3.0e38f, l_run = 0.0f;

  auto stageKV = [&](int buf, int kt){
    const int kv0 = kt * 64;
    const u16* Ksrc = Kp + (size_t)kv0 * 128;
    #pragma unroll
    for (int j = 0; j < 4; j++){
      int n16 = j * 256 + t;
      int row = n16 >> 4, cl = n16 & 15;
      int sc = cl ^ (row & 7);
      gload16(Ksrc + row * 128 + sc * 8, &sK[buf][n16 * 8]);
    }
    const u16* Vsrc = Vp + kv0;
    #pragma unroll
    for (int j = 0; j < 4; j++){
      int n16 = j * 256 + t;
      int row = n16 >> 3, cl = n16 & 7;
      int sc = cl ^ (row & 7);
      gload16(Vsrc + (size_t)row * 2048 + sc * 8, &sV[buf][n16 * 8]);
    }
  };

  stageKV(0, 0);
  asm volatile("s_waitcnt vmcnt(0)" ::: "memory");
  __syncthreads();

  for (int kt = 0; kt < 32; kt++){
    const int cur = kt & 1;
    if (kt + 1 < 32) stageKV(cur ^ 1, kt + 1);
    const u16* sk = sK[cur];
    const u16* sv = sV[cur];

    // QK^T: two 32-kv sub-tiles
    f32x16 p[2];
    #pragma unroll
    for (int kt2 = 0; kt2 < 2; kt2++){
      f32x16 st = (f32x16)(0.0f);
      const int row = kt2*32 + lq;
      const u16* skr = sk + row*128;
      const int rx = row & 7;
      __builtin_amdgcn_s_setprio(1);
      #pragma unroll
      for (int ds = 0; ds < 8; ds++){
        bf16x8 kf = *(const bf16x8*)(skr + (((ds*2 + hi) ^ rx) * 8));
        st = __builtin_amdgcn_mfma_f32_32x32x16_bf16(kf, qf[ds], st, 0, 0, 0);
      }
      __builtin_amdgcn_s_setprio(0);
      p[kt2] = st;
    }

    // online softmax: q = lq is lane-local; partner lane (l^32) has other 32 kv
    float tm = -3.0e38f;
    #pragma unroll
    for (int r = 0; r < 16; r++) tm = fmaxf(tm, fmaxf(p[0][r], p[1][r]));
    tm = fmaxf(tm, __shfl_xor(tm, 32, 64));
    if (!__all(tm <= m_run + 11.0f)){
      float m_new = fmaxf(m_run, tm);
      float corr = exp2_hw(m_run - m_new);   // 0 on first tile
      l_run *= corr;
      #pragma unroll
      for (int r = 0; r < 16; r++){
        float cr = __shfl(corr, (r&3) + 8*(r>>2) + 4*hi, 64);
        acc[0][r] *= cr; acc[1][r] *= cr; acc[2][r] *= cr; acc[3][r] *= cr;
      }
      m_run = m_new;
    }
    float ps = 0.0f;
    #pragma unroll
    for (int kt2 = 0; kt2 < 2; kt2++)
      #pragma unroll
      for (int r = 0; r < 16; r++){
        float v = exp2_hw(p[kt2][r] - m_run);
        p[kt2][r] = v; ps += v;
      }
    ps += __shfl_xor(ps, 32, 64);
    l_run += ps;

    // P -> PV A-frags in-register. For k-slice ks and target half h:
    // words w0,w1 come from half 0's reg-quad (2*ks2+h), w2,w3 from half 1's.
    bf16x8 pa[4];
    #pragma unroll
    for (int kt2 = 0; kt2 < 2; kt2++){
      #pragma unroll
      for (int ks2 = 0; ks2 < 2; ks2++){
        u32 X  = cvtpk_bf16(p[kt2][8*ks2+0], p[kt2][8*ks2+1]);   // P0_{2ks2}
        u32 X2 = cvtpk_bf16(p[kt2][8*ks2+2], p[kt2][8*ks2+3]);   // P1_{2ks2}
        u32 Y  = cvtpk_bf16(p[kt2][8*ks2+4], p[kt2][8*ks2+5]);   // P0_{2ks2+1}
        u32 Y2 = cvtpk_bf16(p[kt2][8*ks2+6], p[kt2][8*ks2+7]);   // P1_{2ks2+1}
        u32 Xo  = (u32)__shfl_xor((int)X,  32, 64);
        u32 X2o = (u32)__shfl_xor((int)X2, 32, 64);
        u32 Yo  = (u32)__shfl_xor((int)Y,  32, 64);
        u32 Y2o = (u32)__shfl_xor((int)Y2, 32, 64);
        u32 W0 = hi ? Yo  : X;
        u32 W1 = hi ? Y2o : X2;
        u32 W2 = hi ? Y   : Xo;
        u32 W3 = hi ? Y2  : X2o;
        pa[kt2*2 + ks2] = mk_bf16x8(W0, W1, W2, W3);
      }
    }

    // PV: acc[dt] += P(32q x 64kv) x V(64kv x 128d)
    #pragma unroll
    for (int ks = 0; ks < 4; ks++){
      __builtin_amdgcn_s_setprio(1);
      #pragma unroll
      for (int dt = 0; dt < 4; dt++){
        const int row = dt*32 + lq;
        bf16x8 vf = *(const bf16x8*)(sv + row*64 + ((((ks<<1) + hi) ^ (row & 7)) * 8));
        acc[dt] = __builtin_amdgcn_mfma_f32_32x32x16_bf16(pa[ks], vf, acc[dt], 0, 0, 0);
      }
      __builtin_amdgcn_s_setprio(0);
    }

    asm volatile("s_waitcnt vmcnt(0)" ::: "memory");
    __syncthreads();
  }

  float linv = 1.0f / l_run;
  #pragma unroll
  for (int r = 0; r < 16; r++){
    int qq = (r&3) + 8*(r>>2) + 4*hi;
    float li = __shfl(linv, qq, 64);
    size_t rowo = ((size_t)b * 2048 + q0 + qq) * 2048 + h*128 + lq;
    #pragma unroll
    for (int dt = 0; dt < 4; dt++)
      O[rowo + dt*32] = f32_bf16(acc[dt][r] * li);
  }
}

extern "C" void kernel_launch(void* const* d_in, const int* in_sizes, int n_in,
                              void* d_out, int out_size, void* d_ws, size_t ws_size,
                              hipStream_t stream)
{
  const float* x   = (const float*)d_in[0];
  const float* Wq  = (const float*)d_in[1];
  const float* bq  = (const float*)d_in[2];
  const float* Wkv = (const float*)d_in[3];
  const float* bkv = (const float*)d_in[4];
  const float* Wo  = (const float*)d_in[5];
  const float* bo  = (const float*)d_in[6];
  float* out = (float*)d_out;

  char* ws = (char*)d_ws;
  size_t off = 0;
  auto alloc = [&](size_t bytes){ void* p = ws + off; off = (off + bytes + 255) & ~(size_t)255; return p; };
  u16* xb     = (u16*)alloc(8388608ull * 2);   // x bf16 [4096][2048]
  u16* WqkvT  = (u16*)alloc(6291456ull * 2);   // [3072][2048]
  u16* WoT    = (u16*)alloc(4194304ull * 2);   // [2048][2048]
  u16* Qb     = (u16*)alloc(8388608ull * 2);   // [B,H,S,D] (pre-scaled)
  u16* Kb     = (u16*)alloc(2097152ull * 2);   // [B,G,S,D]
  u16* VTb    = (u16*)alloc(2097152ull * 2);   // [B,G,D,S]
  u16* Ob     = (u16*)alloc(8388608ull * 2);   // [B,S,E]

  cvt_f32_bf16_k<<<4096, 256, 0, stream>>>(x, xb, 8388608);
  transpose_cvt_k<float><<<dim3(32, 32, 1), 256, 0, stream>>>(Wq,  WqkvT, 2048, 2048);
  transpose_cvt_k<float><<<dim3(16, 32, 1), 256, 0, stream>>>(Wkv, WqkvT + 2048ull*2048ull, 2048, 1024);
  transpose_cvt_k<float><<<dim3(32, 32, 1), 256, 0, stream>>>(Wo,  WoT, 2048, 2048);

  // merged QKV projection: [4096,2048] x [2048,3072]; V written transposed
  gemm256_k<<<dim3(16, 12), 512, 0, stream>>>(xb, WqkvT, bq, bkv, Qb, Kb, VTb, 2048);

  attn_k<<<dim3(16, 32), 256, 0, stream>>>(Qb, Kb, VTb, Ob);

  // output projection: [4096,2048] x [2048,2048] -> f32, 256 blocks (full fill)
  gemm_o_k<<<dim3(16, 16), 512, 0, stream>>>(Ob, WoT, bo, out, 2048);
}